// Round 2
// baseline (387.000 us; speedup 1.0000x reference)
//
#include <hip/hip_runtime.h>
#include <hip/hip_bf16.h>

// PIPNet interface scorer: out[p] = W2 . relu(W1 . concat(g1[il[p]], g2[ir[p]]) + b1) + b2
// R2: coalesced cooperative gather — 16 lanes per 256B feature row.
// R3: pre-convert g1/g2 to bf16 in workspace (streaming, ~64 us) so the random
//     gather reads 128B rows from a 128MB L3-resident working set instead of
//     256B rows from a 256MB HBM-missing one. Falls back to the verified f32
//     gather path if ws_size is too small.
// R4 FIX: in_sizes is ELEMENT counts, not bytes (evidence: out_size==P==1e6
//     elements in the verified baseline). N = in_sizes[i]/64, not /256.

typedef __bf16 bf16x8 __attribute__((ext_vector_type(8)));
typedef float f32x16 __attribute__((ext_vector_type(16)));

__device__ __forceinline__ unsigned f2bf(float f) {
  union { float f; unsigned u; } v;
  v.f = f;
  unsigned u = v.u;
  // round-to-nearest-even f32 -> bf16
  return (u + 0x7fffu + ((u >> 16) & 1u)) >> 16;
}

// Pre-kernel: W1 [128x128] f32 row-major -> bf16 B-fragments for
// v_mfma_f32_32x32x16_bf16; main-loop load is uniform_base + lane*16.
// Fragment (ks, nt, lane): n = lane&31, h = lane>>5;
//   elements = W1[nt*32+n][ks*16 + h*8 + j], j = 0..7
__global__ __launch_bounds__(256) void w1_frag_kernel(
    const float* __restrict__ W1, uint4* __restrict__ w1f) {
  int t = blockIdx.x * 256 + threadIdx.x;  // 0..2047
  int lane = t & 63;
  int nt = (t >> 6) & 3;
  int ks = t >> 8;
  int n = lane & 31, h = lane >> 5;
  const float4* src =
      (const float4*)(W1 + ((nt * 32 + n) * 128 + ks * 16 + h * 8));
  float4 a = src[0], b = src[1];
  uint4 o;
  o.x = f2bf(a.x) | (f2bf(a.y) << 16);
  o.y = f2bf(a.z) | (f2bf(a.w) << 16);
  o.z = f2bf(b.x) | (f2bf(b.y) << 16);
  o.w = f2bf(b.z) | (f2bf(b.w) << 16);
  w1f[t] = o;
}

// Streaming f32 -> bf16 conversion (RNE, identical rounding to f2bf in the
// old gather loop). n8 = number of 8-float chunks.
__global__ __launch_bounds__(256) void cvt_bf16_kernel(
    const float* __restrict__ src, unsigned short* __restrict__ dst, int n8) {
  int i = blockIdx.x * 256 + threadIdx.x;
  const int stride = gridDim.x * 256;
  for (; i < n8; i += stride) {
    const float4* s = (const float4*)(src + (size_t)i * 8);
    float4 a = s[0], b = s[1];
    uint4 o;
    o.x = f2bf(a.x) | (f2bf(a.y) << 16);
    o.y = f2bf(a.z) | (f2bf(a.w) << 16);
    o.z = f2bf(b.x) | (f2bf(b.y) << 16);
    o.w = f2bf(b.z) | (f2bf(b.w) << 16);
    *(uint4*)(dst + (size_t)i * 8) = o;
  }
}

#define LDS_STRIDE 136  // shorts; 272B rows, 16B-aligned for ds_read_b128

template <bool BF16G>
__global__ __launch_bounds__(256, 4) void pip_main_kernel(
    const float* __restrict__ g1, const float* __restrict__ g2,
    const unsigned short* __restrict__ g1b,
    const unsigned short* __restrict__ g2b,
    const int* __restrict__ il, const int* __restrict__ ir,
    const bf16x8* __restrict__ w1f,
    const float* __restrict__ b1, const float* __restrict__ w2,
    const float* __restrict__ b2,
    float* __restrict__ out, int P) {
  __shared__ unsigned short A[128 * LDS_STRIDE];  // 34,816 B -> 4 blocks/CU

  const int t = threadIdx.x;
  const int lane = t & 63;
  const int w = t >> 6;
  const int pair0 = blockIdx.x * 128;

  if (BF16G) {
    // ---- bf16 gather: 8 lanes per (pair,side) row of 64 bf16 (128B) ----
    // Round j covers half-rows r = j*32 + w*8 + g, g = lane>>3. w*8, j*32
    // even => side = r&1 = g&1 fixed per thread; pair = j*16 + (w*8+g)>>1.
    const int sub = lane & 7;            // 16B slice within the 128B row
    const int g = lane >> 3;
    const int side = g & 1;              // 0: left/g1, 1: right/g2
    const int pairB = (w * 8 + g) >> 1;  // 0..15
    const unsigned short* feat = side ? g2b : g1b;
    const int* idxarr = side ? ir : il;

    int idxv[8];
#pragma unroll
    for (int j = 0; j < 8; ++j) {
      int gp = pair0 + j * 16 + pairB;
      int pidx = (gp < P) ? gp : (P - 1);
      idxv[j] = idxarr[pidx];
    }
#pragma unroll
    for (int j = 0; j < 8; ++j) {
      int pair = j * 16 + pairB;
      // 8 consecutive lanes read 128B contiguous; no conversion needed.
      uint4 v = *(const uint4*)(feat + (size_t)idxv[j] * 64 + sub * 8);
      *(uint4*)(A + pair * LDS_STRIDE + side * 64 + sub * 8) = v;
    }
  } else {
    // ---- f32 gather (fallback, verified): 16 lanes per 256B feature row ----
    const int sub = lane & 15;           // lane's 16B slice within the row
    const int g = lane >> 4;
    const int side = g & 1;              // 0: left/g1, 1: right/g2
    const int pairB = (w * 4 + g) >> 1;  // 0..7
    const float* feat = side ? g2 : g1;
    const int* idxarr = side ? ir : il;

    int idxv[16];
#pragma unroll
    for (int j = 0; j < 16; ++j) {
      int gp = pair0 + j * 8 + pairB;
      int pidx = (gp < P) ? gp : (P - 1);
      idxv[j] = idxarr[pidx];
    }
#pragma unroll
    for (int j = 0; j < 16; ++j) {
      int pair = j * 8 + pairB;
      float4 v = *(const float4*)(feat + (size_t)idxv[j] * 64 + sub * 4);
      unsigned lo = f2bf(v.x) | (f2bf(v.y) << 16);
      unsigned hi = f2bf(v.z) | (f2bf(v.w) << 16);
      *(uint2*)(A + pair * LDS_STRIDE + side * 64 + sub * 4) =
          make_uint2(lo, hi);
    }
  }
  __syncthreads();

  // ---- Compute: wave w handles pairs [w*32, w*32+32), full n = 0..127 ----
  const int n = lane & 31;   // MFMA m/n index within tile
  const int h = lane >> 5;   // k-block / row offset half

  f32x16 acc[4];
#pragma unroll
  for (int nt = 0; nt < 4; ++nt)
#pragma unroll
    for (int i = 0; i < 16; ++i) acc[nt][i] = 0.0f;

  const unsigned short* Arow = A + (w * 32 + n) * LDS_STRIDE + h * 8;
#pragma unroll
  for (int ks = 0; ks < 8; ++ks) {
    bf16x8 af = *(const bf16x8*)(Arow + ks * 16);
#pragma unroll
    for (int nt = 0; nt < 4; ++nt) {
      bf16x8 bfr = w1f[(ks * 4 + nt) * 64 + lane];
      acc[nt] = __builtin_amdgcn_mfma_f32_32x32x16_bf16(af, bfr, acc[nt], 0, 0, 0);
    }
  }

  // ---- Epilogue: out[p] = sum_n relu(acc + b1[n]) * w2[n] + b2 ----
  // C/D layout: col(n) = lane&31 (+32*nt), row(m) = (r&3) + 8*(r>>2) + 4*h.
  float b1v[4], w2v[4];
#pragma unroll
  for (int nt = 0; nt < 4; ++nt) {
    b1v[nt] = b1[nt * 32 + n];
    w2v[nt] = w2[nt * 32 + n];
  }
  const float bias2 = b2[0];

#pragma unroll
  for (int r = 0; r < 16; ++r) {
    float s = 0.0f;
#pragma unroll
    for (int nt = 0; nt < 4; ++nt) {
      float v = acc[nt][r] + b1v[nt];
      v = fmaxf(v, 0.0f);
      s = fmaf(v, w2v[nt], s);
    }
    s += __shfl_xor(s, 1);
    s += __shfl_xor(s, 2);
    s += __shfl_xor(s, 4);
    s += __shfl_xor(s, 8);
    s += __shfl_xor(s, 16);
    if (n == 0) {
      int row = (r & 3) + 8 * (r >> 2) + 4 * h;
      int gp = pair0 + w * 32 + row;
      if (gp < P) out[gp] = s + bias2;
    }
  }
}

extern "C" void kernel_launch(void* const* d_in, const int* in_sizes, int n_in,
                              void* d_out, int out_size, void* d_ws, size_t ws_size,
                              hipStream_t stream) {
  const float* g1 = (const float*)d_in[0];   // graph1_x [N,64] f32
  const float* g2 = (const float*)d_in[1];   // graph2_x [N,64] f32
  const int* il = (const int*)d_in[2];       // idx_left [P] int32 (JAX x64 off)
  const int* ir = (const int*)d_in[3];       // idx_right [P] int32
  const float* W1 = (const float*)d_in[4];   // [128,128]
  const float* b1 = (const float*)d_in[5];   // [128]
  const float* w2 = (const float*)d_in[6];   // [1,128]
  const float* b2 = (const float*)d_in[7];   // [1]
  float* out = (float*)d_out;                // [P,1] f32
  const int P = out_size;                    // out_size is ELEMENTS

  // in_sizes is ELEMENT counts (same convention as out_size): N*64 floats.
  const int N1 = in_sizes[0] / 64;
  const int N2 = in_sizes[1] / 64;

  // ws layout: [0,32KB) W1 bf16 B-fragments; then g1 bf16; then g2 bf16.
  // (ws is re-poisoned every call -> rebuild everything each launch.)
  const size_t frag_bytes = 32 * 1024;
  const size_t g1b_bytes = (size_t)N1 * 64 * 2;
  const size_t g2b_bytes = (size_t)N2 * 64 * 2;
  const bool bf16path =
      N1 > 0 && N2 > 0 && ws_size >= frag_bytes + g1b_bytes + g2b_bytes;

  w1_frag_kernel<<<8, 256, 0, stream>>>(W1, (uint4*)d_ws);

  const int nblocks = (P + 127) / 128;
  if (bf16path) {
    unsigned short* g1b = (unsigned short*)((char*)d_ws + frag_bytes);
    unsigned short* g2b = g1b + (size_t)N1 * 64;
    cvt_bf16_kernel<<<2048, 256, 0, stream>>>(g1, g1b, N1 * 8);
    cvt_bf16_kernel<<<2048, 256, 0, stream>>>(g2, g2b, N2 * 8);
    pip_main_kernel<true><<<nblocks, 256, 0, stream>>>(
        g1, g2, g1b, g2b, il, ir, (const bf16x8*)d_ws, b1, w2, b2, out, P);
  } else {
    pip_main_kernel<false><<<nblocks, 256, 0, stream>>>(
        g1, g2, nullptr, nullptr, il, ir, (const bf16x8*)d_ws, b1, w2, b2,
        out, P);
  }
}